// Round 13
// baseline (7844.244 us; speedup 1.0000x reference)
//
#include <hip/hip_runtime.h>
#include <stdint.h>

#define B_ 64
#define T_ 2048
#define F_ 128
#define H_ 256
#define TC_ 1022

typedef __bf16 bf16x8 __attribute__((ext_vector_type(8)));
typedef float f32x4 __attribute__((ext_vector_type(4)));
typedef uint u32x4 __attribute__((ext_vector_type(4)));
typedef unsigned long long u64;

__device__ __forceinline__ ushort f2bf(float f) {
    uint32_t u = __builtin_bit_cast(uint32_t, f);
    u += 0x7FFFu + ((u >> 16) & 1u);
    return (ushort)(u >> 16);
}
__device__ __forceinline__ float sigmoidf_(float x) {
    return __builtin_amdgcn_rcpf(1.f + __expf(-x));
}
__device__ __forceinline__ float tanhf_(float x) {
    x = fminf(15.f, fmaxf(-15.f, x));
    float e = __expf(2.f * x);
    return 1.f - 2.f * __builtin_amdgcn_rcpf(e + 1.f);
}

// ---- Kernel 1: sum of squares over T for F.normalize(dim=1) ----
__global__ __launch_bounds__(128) void k_sqsum(const float* __restrict__ in,
                                               float* __restrict__ sq) {
    int b = blockIdx.x >> 4, tq = blockIdx.x & 15, f = threadIdx.x;
    const float* p = in + ((size_t)b * T_ + (size_t)tq * 128) * F_ + f;
    float acc = 0.f;
#pragma unroll 8
    for (int t = 0; t < 128; ++t) { float v = p[(size_t)t * F_]; acc += v * v; }
    atomicAdd(&sq[b * F_ + f], acc);
}

// ---- Kernel 2: weight repack to bf16 block-row order; bias combine ----
// wbf[g2][m][k]: g2 = unit>>2 (0..63), m = uu*4+gate, k: [0,64)=w_ih, [64,320)=w_hh
__global__ __launch_bounds__(256) void k_prep(const float* __restrict__ wih, const float* __restrict__ whh,
                                              const float* __restrict__ bih, const float* __restrict__ bhh,
                                              ushort* __restrict__ wbf, float* __restrict__ bias) {
    int e = blockIdx.x * 256 + threadIdx.x;
    if (e < 64 * 16 * 320) {
        int g = e / 5120, m = (e / 320) & 15, k = e % 320;
        int j = (m & 3) * 256 + g * 4 + (m >> 2);  // gate*256 + unit
        float v = (k < 64) ? wih[j * 64 + k] : whh[j * 256 + (k - 64)];
        wbf[e] = f2bf(v);
    }
    if (e < 1024) bias[e] = bih[e] + bhh[e];
}

// ---- Kernel 3: fused normalize + conv1d(K=5,S=2) + bias + relu -> li bf16 [tc][b][72pad] ----
__global__ __launch_bounds__(256) void k_conv(const float* __restrict__ in, const float* __restrict__ cw,
                                              const float* __restrict__ cb, const float* __restrict__ sq,
                                              ushort* __restrict__ li) {
    __shared__ float rn[128];
    __shared__ __align__(16) float xs[67 * 129];
    __shared__ __align__(16) float wl[80 * 68];
    int b = blockIdx.x >> 5, tile = blockIdx.x & 31;
    int tc0 = tile * 32;
    int tid = threadIdx.x;
    if (tid < 128) { float ss = sq[b * 128 + tid]; rn[tid] = 1.f / fmaxf(sqrtf(ss), 1e-12f); }
    __syncthreads();
    const float* ip = in + ((size_t)b * T_ + (size_t)(2 * tc0)) * F_;
    for (int i = tid; i < 67 * 128; i += 256) {
        int r = i >> 7, f = i & 127;
        int t = 2 * tc0 + r;
        xs[r * 129 + f] = (t < T_) ? ip[(size_t)r * F_ + f] * rn[f] : 0.f;
    }
    int cg = tid & 15, tcg = tid >> 4;
    float a00 = 0, a01 = 0, a10 = 0, a11 = 0, a20 = 0, a21 = 0, a30 = 0, a31 = 0;
    for (int fc = 0; fc < 8; ++fc) {
        __syncthreads();
        for (int i = tid; i < 64 * 80; i += 256) {
            int c = i / 80, j = i - c * 80;
            wl[j * 68 + c] = cw[c * 640 + fc * 80 + j];
        }
        __syncthreads();
#pragma unroll
        for (int fi = 0; fi < 16; ++fi) {
#pragma unroll
            for (int k = 0; k < 5; ++k) {
                const float4 w4 = *(const float4*)&wl[(fi * 5 + k) * 68 + cg * 4];
                float x0 = xs[(4 * tcg + k) * 129 + fc * 16 + fi];
                float x1 = xs[(4 * tcg + 2 + k) * 129 + fc * 16 + fi];
                a00 += w4.x * x0; a01 += w4.x * x1;
                a10 += w4.y * x0; a11 += w4.y * x1;
                a20 += w4.z * x0; a21 += w4.z * x1;
                a30 += w4.w * x0; a31 += w4.w * x1;
            }
        }
    }
    float bc0 = cb[cg * 4 + 0], bc1 = cb[cg * 4 + 1], bc2 = cb[cg * 4 + 2], bc3 = cb[cg * 4 + 3];
#pragma unroll
    for (int tt = 0; tt < 2; ++tt) {
        int tc = tc0 + tcg * 2 + tt;
        if (tc < TC_) {
            float v0 = fmaxf((tt ? a01 : a00) + bc0, 0.f);
            float v1 = fmaxf((tt ? a11 : a10) + bc1, 0.f);
            float v2 = fmaxf((tt ? a21 : a20) + bc2, 0.f);
            float v3 = fmaxf((tt ? a31 : a30) + bc3, 0.f);
            uint2 pk;
            pk.x = (uint32_t)f2bf(v0) | ((uint32_t)f2bf(v1) << 16);
            pk.y = (uint32_t)f2bf(v2) | ((uint32_t)f2bf(v3) << 16);
            *reinterpret_cast<uint2*>(&li[((size_t)tc * 64 + b) * 72 + cg * 4]) = pk;
        }
    }
}

// ---- Kernel 3b: gx precompute — gx[t][b][1024] = bf16(W_ih @ x_t + b_ih + b_hh).
// UNCHANGED from R11/R12 (correctness-proven, absmax 2.4e-4).
__global__ __launch_bounds__(256, 2) void k_gx(const ushort* __restrict__ li,
                                               const ushort* __restrict__ wbf,
                                               const float* __restrict__ bias,
                                               ushort* __restrict__ gx) {
    int t = blockIdx.x >> 2, bq = blockIdx.x & 3;
    int tid = threadIdx.x;
    int lane = tid & 63, w = tid >> 6, l16 = lane & 15, quad = lane >> 4;
    int b = bq * 16 + l16;
    const ushort* xp = li + ((size_t)t * 64 + b) * 72 + quad * 8;
    bf16x8 x0 = *(const bf16x8*)xp;
    bf16x8 x1 = *(const bf16x8*)(xp + 32);
    ushort* gdst = gx + ((size_t)t * 64 + b) * 1024 + w * 256 + quad * 4;
#pragma unroll
    for (int j = 0; j < 16; ++j) {
        int g2 = w * 16 + j;
        const ushort* wp = wbf + ((size_t)(g2 * 16 + l16)) * 320 + quad * 8;
        bf16x8 a0 = *(const bf16x8*)wp;
        bf16x8 a1 = *(const bf16x8*)(wp + 32);
        f32x4 A = {0.f, 0.f, 0.f, 0.f};
        A = __builtin_amdgcn_mfma_f32_16x16x32_bf16(a0, x0, A, 0, 0, 0);
        A = __builtin_amdgcn_mfma_f32_16x16x32_bf16(a1, x1, A, 0, 0, 0);
        int u = g2 * 4 + quad;
        uint2 pk;
        pk.x = (uint)f2bf(A[0] + bias[u]) | ((uint)f2bf(A[1] + bias[256 + u]) << 16);
        pk.y = (uint)f2bf(A[2] + bias[512 + u]) | ((uint)f2bf(A[3] + bias[768 + u]) << 16);
        *(uint2*)(gdst + j * 16) = pk;
    }
}

// ---- Kernel 4: SINGLE-CU COMMUNICATION-FREE LSTM scan, v3.
// R12 post-mortem: launch_bounds(512,2) -> VGPR cap 128 (interpreted as 2 blocks/CU ->
// 4 waves/SIMD); af[8][5]=160 spilled -> 6.4ms scratch-bound. Fixes:
//  (1) launch_bounds(512,1): 8 waves x 256 VGPR = the full 2048-reg CU file (R11
//      evidence: (256,1)->256). LDS 156KB caps at 1 block/CU anyway.
//  (2) Pressure trim: regs hold s=0..3 only (af[8][4]=128 VGPR); s=4 streamed from
//      L2 at step top (dies at use); s=7 j=1..7 streamed after the s=4 phase; LDS
//      holds s=5,6 (all j) + s=7 j=0 -> 17 slots/wave, 136KB. Peak ~231 VGPR.
//  (3) Hs DOUBLE-BUFFERED (2x8.4KB) -> ONE barrier/step (R8-proven argument), so
//      waves skew: one wave's trans-heavy epilogue overlaps the sibling wave's
//      MFMAs on the same SIMD (m114). Step ~ max(MFMA 2483cy, epi ~2080cy).
// All correctness-bearing pieces (fill swizzle, fragment formulas, gx layout,
// epilogue mapping) verbatim from the PASSING R12 kernel.
__global__ __launch_bounds__(512, 1) void k_scan2(const ushort* __restrict__ gx,
                                                  const ushort* __restrict__ wbf,
                                                  float* __restrict__ hfin) {
    __shared__ __align__(16) ushort wlds[136 * 512];  // 139264 B: 136 frag-slots x 1KB
    __shared__ __align__(16) ushort Hs[2][16 * 264];  // 16896 B: dbuf h [b:16][256+8 pad]
    int p = blockIdx.x;
    int tid = threadIdx.x;
    int lane = tid & 63, w = tid >> 6, l16 = lane & 15, quad = lane >> 4;
    int bb = p * 16 + l16;
    // ---- cooperative LDS weight fill: slot = wv*17 + L; L<16 -> (j=L>>1, s=5+(L&1));
    // L==16 -> (j=0, s=7). chunk c of row stored at c^((row>>1)&3) (R12-proven).
    for (int i = tid; i < 136 * 64; i += 512) {
        int slot = i >> 6, ch = i & 63;
        int row = ch >> 2, c = ch & 3, cp = c ^ ((row >> 1) & 3);
        int wv = slot / 17, L = slot - wv * 17;
        int j = (L < 16) ? (L >> 1) : 0;
        int s = (L < 16) ? (5 + (L & 1)) : 7;
        int g2 = wv * 8 + j;
        const ushort* src = wbf + ((size_t)(g2 * 16 + row)) * 320 + (s + 2) * 32 + c * 8;
        *(uint4*)&wlds[slot * 512 + row * 32 + cp * 8] = *(const uint4*)src;
    }
    // ---- stationary reg frags: s=0..3 for all 8 tiles (all indices literal) ----
    bf16x8 af[8][4];
#pragma unroll
    for (int j = 0; j < 8; ++j) {
        const ushort* wp = wbf + ((size_t)((w * 8 + j) * 16 + l16)) * 320 + quad * 8;
#pragma unroll
        for (int s = 0; s < 4; ++s) af[j][s] = *(const bf16x8*)(wp + (s + 2) * 32);
    }
    float cs[8];
#pragma unroll
    for (int j = 0; j < 8; ++j) cs[j] = 0.f;
    // streamed-weight bases: s=4 (j=0..7), s=7 (j=1..7); stride between j's = 5120 ushorts
    const ushort* sw4 = wbf + ((size_t)((w * 8) * 16 + l16)) * 320 + 6 * 32 + quad * 8;
    const ushort* sw7 = wbf + ((size_t)((w * 8 + 1) * 16 + l16)) * 320 + 9 * 32 + quad * 8;
    const int lsw = quad ^ ((l16 >> 1) & 3);  // LDS read chunk (matches fill swizzle)
    const ushort* gxb = gx + (size_t)bb * 1024 + w * 128 + quad * 4;
    __syncthreads();  // wlds fill complete
#pragma unroll 1
    for (int t = 0; t < TC_; ++t) {
        const ushort* gxr = gxb + (size_t)t * 65536;
        // gx gates for all 8 tiles issued at step top (streaming; used ~2k cy later).
        uint2 gq0[4], gq1[4];
#pragma unroll
        for (int j = 0; j < 4; ++j) gq0[j] = *(const uint2*)(gxr + j * 16);
#pragma unroll
        for (int j = 0; j < 4; ++j) gq1[j] = *(const uint2*)(gxr + 64 + j * 16);
        // streamed s=4 weights (L2-hot: same addr every step); die at the s=4 phase.
        bf16x8 sf4[8];
#pragma unroll
        for (int m = 0; m < 8; ++m) sf4[m] = *(const bf16x8*)(sw4 + (size_t)m * 5120);
        f32x4 A[8];
#pragma unroll
        for (int j = 0; j < 8; ++j) A[j] = (f32x4){0.f, 0.f, 0.f, 0.f};
        const char* hr = (const char*)Hs[(t + 1) & 1];  // h(t-1) buffer
        char* hw = (char*)Hs[t & 1];                    // h(t) buffer
        if (t > 0) {
            // s=0..3: reg weights.
#pragma unroll
            for (int s = 0; s < 4; ++s) {
                bf16x8 bh = *(const bf16x8*)(hr + l16 * 528 + s * 64 + quad * 16);
#pragma unroll
                for (int j = 0; j < 8; ++j)
                    A[j] = __builtin_amdgcn_mfma_f32_16x16x32_bf16(af[j][s], bh, A[j], 0, 0, 0);
            }
            // s=4: streamed weights.
            {
                bf16x8 bh = *(const bf16x8*)(hr + l16 * 528 + 4 * 64 + quad * 16);
#pragma unroll
                for (int j = 0; j < 8; ++j)
                    A[j] = __builtin_amdgcn_mfma_f32_16x16x32_bf16(sf4[j], bh, A[j], 0, 0, 0);
            }
            // streamed s=7 weights j=1..7 issued now (L2-hot, ~2 MFMA phases to land).
            bf16x8 sf7[7];
#pragma unroll
            for (int m = 0; m < 7; ++m) sf7[m] = *(const bf16x8*)(sw7 + (size_t)m * 5120);
            // s=5,6: LDS weights.
#pragma unroll
            for (int s = 5; s < 7; ++s) {
                bf16x8 bh = *(const bf16x8*)(hr + l16 * 528 + s * 64 + quad * 16);
#pragma unroll
                for (int j = 0; j < 8; ++j) {
                    bf16x8 a = *(const bf16x8*)&wlds[(w * 17 + j * 2 + (s - 5)) * 512 + l16 * 32 + lsw * 8];
                    A[j] = __builtin_amdgcn_mfma_f32_16x16x32_bf16(a, bh, A[j], 0, 0, 0);
                }
            }
            // s=7: j=0 LDS; j=1..7 streamed regs.
            {
                bf16x8 bh = *(const bf16x8*)(hr + l16 * 528 + 7 * 64 + quad * 16);
                bf16x8 a0 = *(const bf16x8*)&wlds[(w * 17 + 16) * 512 + l16 * 32 + lsw * 8];
                A[0] = __builtin_amdgcn_mfma_f32_16x16x32_bf16(a0, bh, A[0], 0, 0, 0);
#pragma unroll
                for (int j = 1; j < 8; ++j)
                    A[j] = __builtin_amdgcn_mfma_f32_16x16x32_bf16(sf7[j - 1], bh, A[j], 0, 0, 0);
            }
        }
        // Epilogue (no barrier before it: each wave needs only its OWN A[]; h-writes go
        // to hw which no wave reads this step — dbuf. Waves skew -> MFMA/VALU overlap.)
        bool lastt = (t == TC_ - 1);
#pragma unroll
        for (int j = 0; j < 8; ++j) {
            uint2 g = (j < 4) ? gq0[j] : gq1[j - 4];  // literal select after unroll
            float x0 = __builtin_bit_cast(float, g.x << 16);
            float x1 = __builtin_bit_cast(float, g.x & 0xFFFF0000u);
            float x2 = __builtin_bit_cast(float, g.y << 16);
            float x3 = __builtin_bit_cast(float, g.y & 0xFFFF0000u);
            float gi = A[j][0] + x0, gf = A[j][1] + x1;
            float gg = A[j][2] + x2, go = A[j][3] + x3;
            float ii = sigmoidf_(gi), ff = sigmoidf_(gf), gv = tanhf_(gg), oo = sigmoidf_(go);
            cs[j] = ff * cs[j] + ii * gv;
            float hv = oo * tanhf_(cs[j]);
            int u = w * 32 + j * 4 + quad;
            if (lastt) {
                hfin[u * 64 + bb] = hv;
            } else {
                ushort hb = f2bf(hv);
                uint pr = ((uint)hb) | ((uint)__shfl((int)hb, (lane + 16) & 63) << 16);
                if ((quad & 1) == 0)
                    *(uint*)(hw + l16 * 528 + u * 2) = pr;  // units u, u+1
            }
        }
        // ONE barrier/step: h(t) writes visible before step t+1 reads; also protects
        // hw(t+1)=hr(t-1)'s overwrite (all waves' step-t reads precede this barrier).
        __syncthreads();
    }
}

// ---- Kernel 4-FALLBACK (R8-proven, 2.41ms): used when ws_size can't hold gx. ----
__global__ __launch_bounds__(512) void k_scan(const ushort* __restrict__ li,
                                              const ushort* __restrict__ wbf,
                                              const float* __restrict__ bias,
                                              u64* __restrict__ hbuf,
                                              float* __restrict__ hfin) {
    __shared__ __align__(16) ushort Hs[2][16 * 264];
    int p = blockIdx.x & 7, q = blockIdx.x >> 3;
    if (p >= 4) return;
    int tid = threadIdx.x;
    int lane = tid & 63, wave = tid >> 6, l16 = lane & 15, quad = lane >> 4;
    int bb = p * 16 + l16;
    int g2a = q * 16 + 2 * wave, g2b = g2a + 1;
    int u0 = g2a * 4 + quad, u1 = g2b * 4 + quad;
    int pc = 32 * q + 4 * wave + (quad >> 1);
    bf16x8 af0[10], af1[10];
    const ushort* wp0 = wbf + ((size_t)(g2a * 16 + l16)) * 320 + quad * 8;
    const ushort* wp1 = wbf + ((size_t)(g2b * 16 + l16)) * 320 + quad * 8;
#pragma unroll
    for (int s = 0; s < 10; ++s) { af0[s] = *(const bf16x8*)(wp0 + s * 32);
                                   af1[s] = *(const bf16x8*)(wp1 + s * 32); }
    float bi0 = bias[u0], bf0 = bias[256 + u0], bg0 = bias[512 + u0], bo0 = bias[768 + u0];
    float bi1 = bias[u1], bf1 = bias[256 + u1], bg1 = bias[512 + u1], bo1 = bias[768 + u1];
    float cs0 = 0.f, cs1 = 0.f;
    bool broken = false;
    const ushort* xpp = li + ((size_t)0 * 64 + bb) * 72 + quad * 8;
    bf16x8 x0 = *(const bf16x8*)xpp;
    bf16x8 x1 = *(const bf16x8*)(xpp + 32);
#pragma unroll 1
    for (int t = 0; t < TC_; ++t) {
        f32x4 A0 = {0.f, 0.f, 0.f, 0.f}, A1 = {0.f, 0.f, 0.f, 0.f};
        A0 = __builtin_amdgcn_mfma_f32_16x16x32_bf16(af0[0], x0, A0, 0, 0, 0);
        A1 = __builtin_amdgcn_mfma_f32_16x16x32_bf16(af1[0], x0, A1, 0, 0, 0);
        A0 = __builtin_amdgcn_mfma_f32_16x16x32_bf16(af0[1], x1, A0, 0, 0, 0);
        A1 = __builtin_amdgcn_mfma_f32_16x16x32_bf16(af1[1], x1, A1, 0, 0, 0);
        char* hb = (char*)Hs + (size_t)(t & 1) * (16 * 264 * 2);
        if (t > 0) {
            uint tg = (uint)(t - 1);
            const u64* src = hbuf + ((size_t)((t - 1) & 1) << 13) + p * 2048 + tid * 4;
            u64 vv0, vv1, vv2, vv3;
            bool got = false;
            if (!broken) {
                u32x4 pa, pb;
                bool ok;
                int guard = 0;
                do {
                    asm volatile(
                        "global_load_dwordx4 %0, %2, off sc0\n\t"
                        "global_load_dwordx4 %1, %2, off offset:16 sc0\n\t"
                        "s_waitcnt vmcnt(0)"
                        : "=&v"(pa), "=&v"(pb) : "v"(src) : "memory");
                    uint m = ((pa.x >> 16) ^ tg) | ((pa.y >> 16) ^ tg)
                           | ((pa.z >> 16) ^ tg) | ((pa.w >> 16) ^ tg)
                           | ((pb.x >> 16) ^ tg) | ((pb.y >> 16) ^ tg)
                           | ((pb.z >> 16) ^ tg) | ((pb.w >> 16) ^ tg);
                    ok = (m == 0);
                } while (!__all(ok) && ++guard < 1024);
                got = __all(ok);
                if (got) {
                    vv0 = ((u64)pa.y << 32) | pa.x;
                    vv1 = ((u64)pa.w << 32) | pa.z;
                    vv2 = ((u64)pb.y << 32) | pb.x;
                    vv3 = ((u64)pb.w << 32) | pb.z;
                } else broken = true;
            }
            if (!got) {
                u64 w0, w1, w2, w3;
                bool ok;
                int guard = 0;
                do {
                    w0 = __hip_atomic_load(src + 0, __ATOMIC_RELAXED, __HIP_MEMORY_SCOPE_AGENT);
                    w1 = __hip_atomic_load(src + 1, __ATOMIC_RELAXED, __HIP_MEMORY_SCOPE_AGENT);
                    w2 = __hip_atomic_load(src + 2, __ATOMIC_RELAXED, __HIP_MEMORY_SCOPE_AGENT);
                    w3 = __hip_atomic_load(src + 3, __ATOMIC_RELAXED, __HIP_MEMORY_SCOPE_AGENT);
                    uint m = (((uint)(w0 >> 16) & 0xFFFFu) ^ tg) | (((uint)(w0 >> 48)) ^ tg);
                    m |= (((uint)(w1 >> 16) & 0xFFFFu) ^ tg) | (((uint)(w1 >> 48)) ^ tg);
                    m |= (((uint)(w2 >> 16) & 0xFFFFu) ^ tg) | (((uint)(w2 >> 48)) ^ tg);
                    m |= (((uint)(w3 >> 16) & 0xFFFFu) ^ tg) | (((uint)(w3 >> 48)) ^ tg);
                    ok = (m == 0);
                } while (!__all(ok) && ++guard < (1 << 14));
                vv0 = w0; vv1 = w1; vv2 = w2; vv3 = w3;
            }
            {
                int b = tid >> 5, c0 = (tid * 4) & 127;
                uint4 wv;
                wv.x = ((uint)vv0 & 0xFFFFu) | (((uint)(vv0 >> 32) & 0xFFFFu) << 16);
                wv.y = ((uint)vv1 & 0xFFFFu) | (((uint)(vv1 >> 32) & 0xFFFFu) << 16);
                wv.z = ((uint)vv2 & 0xFFFFu) | (((uint)(vv2 >> 32) & 0xFFFFu) << 16);
                wv.w = ((uint)vv3 & 0xFFFFu) | (((uint)(vv3 >> 32) & 0xFFFFu) << 16);
                *(uint4*)(hb + b * 528 + c0 * 4) = wv;
            }
            __syncthreads();
#pragma unroll
            for (int s = 0; s < 8; ++s) {
                bf16x8 bh = *(const bf16x8*)(hb + l16 * 528 + s * 64 + quad * 16);
                A0 = __builtin_amdgcn_mfma_f32_16x16x32_bf16(af0[2 + s], bh, A0, 0, 0, 0);
                A1 = __builtin_amdgcn_mfma_f32_16x16x32_bf16(af1[2 + s], bh, A1, 0, 0, 0);
            }
        }
        float hv0, hv1;
        {
            float gi = A0[0] + bi0, gf = A0[1] + bf0, gg = A0[2] + bg0, go = A0[3] + bo0;
            float ii = sigmoidf_(gi), ff = sigmoidf_(gf), g2 = tanhf_(gg), oo = sigmoidf_(go);
            cs0 = ff * cs0 + ii * g2;
            hv0 = oo * tanhf_(cs0);
        }
        {
            float gi = A1[0] + bi1, gf = A1[1] + bf1, gg = A1[2] + bg1, go = A1[3] + bo1;
            float ii = sigmoidf_(gi), ff = sigmoidf_(gf), g2 = tanhf_(gg), oo = sigmoidf_(go);
            cs1 = ff * cs1 + ii * g2;
            hv1 = oo * tanhf_(cs1);
        }
        if (t == TC_ - 1) {
            hfin[u0 * 64 + bb] = hv0;
            hfin[u1 * 64 + bb] = hv1;
        } else {
            ushort h0 = f2bf(hv0), h1 = f2bf(hv1);
            uint pr0 = ((uint)h0 & 0xFFFFu) | ((uint)__shfl((int)h0, (lane + 16) & 63) << 16);
            uint pr1 = ((uint)h1 & 0xFFFFu) | ((uint)__shfl((int)h1, (lane + 16) & 63) << 16);
            if ((quad & 1) == 0) {
                uint tg2 = ((uint)t) << 16;
                u64 w0 = (u64)((pr0 & 0xFFFFu) | tg2) | ((u64)((pr0 >> 16) | tg2) << 32);
                u64 w1 = (u64)((pr1 & 0xFFFFu) | tg2) | ((u64)((pr1 >> 16) | tg2) << 32);
                u64* dst = hbuf + ((size_t)(t & 1) << 13) + p * 2048 + l16 * 128;
                __hip_atomic_store(dst + pc, w0, __ATOMIC_RELAXED, __HIP_MEMORY_SCOPE_AGENT);
                __hip_atomic_store(dst + pc + 2, w1, __ATOMIC_RELAXED, __HIP_MEMORY_SCOPE_AGENT);
            }
        }
        int tn = (t + 1 < TC_) ? t + 1 : t;
        const ushort* xpn = li + ((size_t)tn * 64 + bb) * 72 + quad * 8;
        x0 = *(const bf16x8*)xpn;
        x1 = *(const bf16x8*)(xpn + 32);
    }
}

// ---- Kernel 5: out[b][o] = h_final[:,b] . lin_w[o,:] + lin_b[o] ----
__global__ __launch_bounds__(64) void k_fin(const float* __restrict__ hfin, const float* __restrict__ lw,
                                            const float* __restrict__ lb, float* __restrict__ out) {
    int o = blockIdx.x, b = threadIdx.x;
    float acc = lb[o];
    const float* wp = lw + o * 256;
#pragma unroll 4
    for (int u2 = 0; u2 < 256; ++u2) acc += hfin[u2 * 64 + b] * wp[u2];
    out[b * 10 + o] = acc;
}

extern "C" void kernel_launch(void* const* d_in, const int* in_sizes, int n_in,
                              void* d_out, int out_size, void* d_ws, size_t ws_size,
                              hipStream_t stream) {
    const float* in  = (const float*)d_in[0];
    // d_in[1] ("r") unused
    const float* cw  = (const float*)d_in[2];
    const float* cb  = (const float*)d_in[3];
    const float* wih = (const float*)d_in[4];
    const float* whh = (const float*)d_in[5];
    const float* bih = (const float*)d_in[6];
    const float* bhh = (const float*)d_in[7];
    const float* lw  = (const float*)d_in[8];
    const float* lb  = (const float*)d_in[9];
    float* out = (float*)d_out;

    char* ws = (char*)d_ws;
    float*  sq   = (float*)(ws + 0);          // 32768 B
    u64*    hbuf = (u64*)(ws + 32768);        // 131072 B (fallback exchange buffer)
    float*  bias = (float*)(ws + 163840);     // 4096 B
    float*  hfin = (float*)(ws + 167936);     // 65536 B  [u][b] fp32
    ushort* wbf  = (ushort*)(ws + 233472);    // 655360 B [g2][16][320] bf16
    ushort* li   = (ushort*)(ws + 888832);    // 9418752 B [tc][b][72] bf16
    ushort* gx   = (ushort*)(ws + 10307584);  // 133955584 B [tc][b][1024] bf16
    const size_t WS_NEED = 10307584ull + 133955584ull;  // 144,263,168

    hipMemsetAsync(sq, 0, 32768, stream);

    k_sqsum<<<1024, 128, 0, stream>>>(in, sq);
    k_prep<<<1280, 256, 0, stream>>>(wih, whh, bih, bhh, wbf, bias);
    k_conv<<<2048, 256, 0, stream>>>(in, cw, cb, sq, li);
    if (ws_size >= WS_NEED) {
        // Communication-free path: precompute gx, then 4 independent single-CU scans.
        k_gx<<<TC_ * 4, 256, 0, stream>>>(li, wbf, bias, gx);
        k_scan2<<<4, 512, 0, stream>>>(gx, wbf, hfin);
    } else {
        // Fallback: R8-proven pod exchange (2.41 ms).
        hipMemsetAsync(hbuf, 0xFF, 131072, stream);
        k_scan<<<32, 512, 0, stream>>>(li, wbf, bias, hbuf, hfin);
    }
    k_fin<<<10, 64, 0, stream>>>(hfin, lw, lb, out);
}

// Round 14
// 7308.088 us; speedup vs baseline: 1.0734x; 1.0734x over previous
//
#include <hip/hip_runtime.h>
#include <stdint.h>

#define B_ 64
#define T_ 2048
#define F_ 128
#define H_ 256
#define TC_ 1022

typedef __bf16 bf16x8 __attribute__((ext_vector_type(8)));
typedef float f32x4 __attribute__((ext_vector_type(4)));
typedef uint u32x4 __attribute__((ext_vector_type(4)));
typedef unsigned long long u64;

__device__ __forceinline__ ushort f2bf(float f) {
    uint32_t u = __builtin_bit_cast(uint32_t, f);
    u += 0x7FFFu + ((u >> 16) & 1u);
    return (ushort)(u >> 16);
}
__device__ __forceinline__ float sigmoidf_(float x) {
    return __builtin_amdgcn_rcpf(1.f + __expf(-x));
}
__device__ __forceinline__ float tanhf_(float x) {
    x = fminf(15.f, fmaxf(-15.f, x));
    float e = __expf(2.f * x);
    return 1.f - 2.f * __builtin_amdgcn_rcpf(e + 1.f);
}

// ---- Kernel 1: sum of squares over T for F.normalize(dim=1) ----
__global__ __launch_bounds__(128) void k_sqsum(const float* __restrict__ in,
                                               float* __restrict__ sq) {
    int b = blockIdx.x >> 4, tq = blockIdx.x & 15, f = threadIdx.x;
    const float* p = in + ((size_t)b * T_ + (size_t)tq * 128) * F_ + f;
    float acc = 0.f;
#pragma unroll 8
    for (int t = 0; t < 128; ++t) { float v = p[(size_t)t * F_]; acc += v * v; }
    atomicAdd(&sq[b * F_ + f], acc);
}

// ---- Kernel 2: weight repack to bf16 block-row order; bias combine ----
// wbf[g2][m][k]: g2 = unit>>2 (0..63), m = uu*4+gate, k: [0,64)=w_ih, [64,320)=w_hh
__global__ __launch_bounds__(256) void k_prep(const float* __restrict__ wih, const float* __restrict__ whh,
                                              const float* __restrict__ bih, const float* __restrict__ bhh,
                                              ushort* __restrict__ wbf, float* __restrict__ bias) {
    int e = blockIdx.x * 256 + threadIdx.x;
    if (e < 64 * 16 * 320) {
        int g = e / 5120, m = (e / 320) & 15, k = e % 320;
        int j = (m & 3) * 256 + g * 4 + (m >> 2);  // gate*256 + unit
        float v = (k < 64) ? wih[j * 64 + k] : whh[j * 256 + (k - 64)];
        wbf[e] = f2bf(v);
    }
    if (e < 1024) bias[e] = bih[e] + bhh[e];
}

// ---- Kernel 3: fused normalize + conv1d(K=5,S=2) + bias + relu -> li bf16 [tc][b][72pad] ----
__global__ __launch_bounds__(256) void k_conv(const float* __restrict__ in, const float* __restrict__ cw,
                                              const float* __restrict__ cb, const float* __restrict__ sq,
                                              ushort* __restrict__ li) {
    __shared__ float rn[128];
    __shared__ __align__(16) float xs[67 * 129];
    __shared__ __align__(16) float wl[80 * 68];
    int b = blockIdx.x >> 5, tile = blockIdx.x & 31;
    int tc0 = tile * 32;
    int tid = threadIdx.x;
    if (tid < 128) { float ss = sq[b * 128 + tid]; rn[tid] = 1.f / fmaxf(sqrtf(ss), 1e-12f); }
    __syncthreads();
    const float* ip = in + ((size_t)b * T_ + (size_t)(2 * tc0)) * F_;
    for (int i = tid; i < 67 * 128; i += 256) {
        int r = i >> 7, f = i & 127;
        int t = 2 * tc0 + r;
        xs[r * 129 + f] = (t < T_) ? ip[(size_t)r * F_ + f] * rn[f] : 0.f;
    }
    int cg = tid & 15, tcg = tid >> 4;
    float a00 = 0, a01 = 0, a10 = 0, a11 = 0, a20 = 0, a21 = 0, a30 = 0, a31 = 0;
    for (int fc = 0; fc < 8; ++fc) {
        __syncthreads();
        for (int i = tid; i < 64 * 80; i += 256) {
            int c = i / 80, j = i - c * 80;
            wl[j * 68 + c] = cw[c * 640 + fc * 80 + j];
        }
        __syncthreads();
#pragma unroll
        for (int fi = 0; fi < 16; ++fi) {
#pragma unroll
            for (int k = 0; k < 5; ++k) {
                const float4 w4 = *(const float4*)&wl[(fi * 5 + k) * 68 + cg * 4];
                float x0 = xs[(4 * tcg + k) * 129 + fc * 16 + fi];
                float x1 = xs[(4 * tcg + 2 + k) * 129 + fc * 16 + fi];
                a00 += w4.x * x0; a01 += w4.x * x1;
                a10 += w4.y * x0; a11 += w4.y * x1;
                a20 += w4.z * x0; a21 += w4.z * x1;
                a30 += w4.w * x0; a31 += w4.w * x1;
            }
        }
    }
    float bc0 = cb[cg * 4 + 0], bc1 = cb[cg * 4 + 1], bc2 = cb[cg * 4 + 2], bc3 = cb[cg * 4 + 3];
#pragma unroll
    for (int tt = 0; tt < 2; ++tt) {
        int tc = tc0 + tcg * 2 + tt;
        if (tc < TC_) {
            float v0 = fmaxf((tt ? a01 : a00) + bc0, 0.f);
            float v1 = fmaxf((tt ? a11 : a10) + bc1, 0.f);
            float v2 = fmaxf((tt ? a21 : a20) + bc2, 0.f);
            float v3 = fmaxf((tt ? a31 : a30) + bc3, 0.f);
            uint2 pk;
            pk.x = (uint32_t)f2bf(v0) | ((uint32_t)f2bf(v1) << 16);
            pk.y = (uint32_t)f2bf(v2) | ((uint32_t)f2bf(v3) << 16);
            *reinterpret_cast<uint2*>(&li[((size_t)tc * 64 + b) * 72 + cg * 4]) = pk;
        }
    }
}

// ---- Kernel 4: pod LSTM scan, 2-BLOCK pods (tail-of-N visibility test on R8 chassis).
// Ledger: 11 exchange variants flat at ~5-6k cy/step; single-CU bf16 closed (weight
// streaming >= 150KB/step/CU from L2 = BW floor above R8). Last untested variable on the
// PROVEN chassis: pod width. Rendezvous = max over N producers of store-to-visible; if
// that delay has variance, E[max of 2] < E[max of 4]. This kernel: 4 pods x 2 blocks
// (1024 thr, 16 waves x 2 M-tiles = 128 units/block), placement p=blockIdx%8 with
// blocks {p, p+8} -> same XCD (R6-proven). Poll halves: 2 cells/thread = ONE dwordx4.
// Protocol verbatim R8: tagged cells (tag in each 32b half -> torn plain reads are
// self-detecting), parity dbuf, atomic publish + plain-sc0 fast poll with sticky
// atomic-poll fallback, Hs dbuf + single barrier/step. Chain argument (skew<=1) is
// participant-count-independent: publishing t requires having polled all tags(t-1),
// and a sibling's tag(t-1) implies its poll(t-2) completed.
__global__ __launch_bounds__(1024) void k_scan(const ushort* __restrict__ li,
                                               const ushort* __restrict__ wbf,
                                               const float* __restrict__ bias,
                                               u64* __restrict__ hbuf,
                                               float* __restrict__ hfin) {
    __shared__ __align__(16) ushort Hs[2][16 * 264];  // dbuf: h [b:16][256+8 pad], rows 528B
    int p = blockIdx.x & 7, q = blockIdx.x >> 3;      // pod/XCD, role (0/1)
    if (p >= 4) return;                               // pods on XCDs 0-3; others exit
    int tid = threadIdx.x;
    int lane = tid & 63, wave = tid >> 6, l16 = lane & 15, quad = lane >> 4;
    int bb = p * 16 + l16;                            // global batch
    int g2a = q * 32 + wave * 2, g2b = g2a + 1;       // this wave's two M-tiles
    int u0 = g2a * 4 + quad, u1 = g2b * 4 + quad;
    int pc = 2 * g2a + (quad >> 1);                   // publish pair-cell (tile a; tile b = +2)
    // Stationary A-fragments: two 16-row tiles (rows = l16 within each tile).
    bf16x8 af0[10], af1[10];
    const ushort* wp0 = wbf + ((size_t)(g2a * 16 + l16)) * 320 + quad * 8;
    const ushort* wp1 = wbf + ((size_t)(g2b * 16 + l16)) * 320 + quad * 8;
#pragma unroll
    for (int s = 0; s < 10; ++s) { af0[s] = *(const bf16x8*)(wp0 + s * 32);
                                   af1[s] = *(const bf16x8*)(wp1 + s * 32); }
    float bi0 = bias[u0], bf0 = bias[256 + u0], bg0 = bias[512 + u0], bo0 = bias[768 + u0];
    float bi1 = bias[u1], bf1 = bias[256 + u1], bg1 = bias[512 + u1], bo1 = bias[768 + u1];
    float cs0 = 0.f, cs1 = 0.f;
    bool broken = false;
    // xt preload for t=0 (B-frags shared by both M-tiles)
    const ushort* xpp = li + ((size_t)0 * 64 + bb) * 72 + quad * 8;
    bf16x8 x0 = *(const bf16x8*)xpp;
    bf16x8 x1 = *(const bf16x8*)(xpp + 32);
#pragma unroll 1
    for (int t = 0; t < TC_; ++t) {
        f32x4 A0 = {0.f, 0.f, 0.f, 0.f}, A1 = {0.f, 0.f, 0.f, 0.f};
        // x-part MFMAs first (xt already in regs from prefetch).
        A0 = __builtin_amdgcn_mfma_f32_16x16x32_bf16(af0[0], x0, A0, 0, 0, 0);
        A1 = __builtin_amdgcn_mfma_f32_16x16x32_bf16(af1[0], x0, A1, 0, 0, 0);
        A0 = __builtin_amdgcn_mfma_f32_16x16x32_bf16(af0[1], x1, A0, 0, 0, 0);
        A1 = __builtin_amdgcn_mfma_f32_16x16x32_bf16(af1[1], x1, A1, 0, 0, 0);
        char* hb = (char*)Hs + (size_t)(t & 1) * (16 * 264 * 2);
        if (t > 0) {
            uint tg = (uint)(t - 1);
            // This thread's 2 cells of the pod image: ONE dwordx4.
            const u64* src = hbuf + ((size_t)((t - 1) & 1) << 13) + p * 2048 + tid * 2;
            u64 vv0, vv1;
            bool got = false;
            if (!broken) {
                // FAST poll: plain sc0 dwordx4 (L1-bypass, L2-served).
                u32x4 pa;
                bool ok;
                int guard = 0;
                do {
                    asm volatile(
                        "global_load_dwordx4 %0, %1, off sc0\n\t"
                        "s_waitcnt vmcnt(0)"
                        : "=&v"(pa) : "v"(src) : "memory");
                    uint m = ((pa.x >> 16) ^ tg) | ((pa.y >> 16) ^ tg)
                           | ((pa.z >> 16) ^ tg) | ((pa.w >> 16) ^ tg);
                    ok = (m == 0);
                } while (!__all(ok) && ++guard < 1024);
                got = __all(ok);
                if (got) {
                    vv0 = ((u64)pa.y << 32) | pa.x;
                    vv1 = ((u64)pa.w << 32) | pa.z;
                } else broken = true;  // sticky: this wave polls atomically from now on
            }
            if (!got) {
                // Fallback: R6/R8-proven atomic-load poll on the SAME cells.
                u64 w0, w1;
                bool ok;
                int guard = 0;
                do {
                    w0 = __hip_atomic_load(src + 0, __ATOMIC_RELAXED, __HIP_MEMORY_SCOPE_AGENT);
                    w1 = __hip_atomic_load(src + 1, __ATOMIC_RELAXED, __HIP_MEMORY_SCOPE_AGENT);
                    uint m = (((uint)(w0 >> 16) & 0xFFFFu) ^ tg) | (((uint)(w0 >> 48)) ^ tg);
                    m |= (((uint)(w1 >> 16) & 0xFFFFu) ^ tg) | (((uint)(w1 >> 48)) ^ tg);
                    ok = (m == 0);
                } while (!__all(ok) && ++guard < (1 << 14));
                vv0 = w0; vv1 = w1;
            }
            // Stage 2 cells: idx = 2*tid -> b = tid>>6 (=wave), c0 = (tid&63)*2.
            {
                int b = tid >> 6, c0 = (tid & 63) * 2;
                uint2 w;
                w.x = ((uint)vv0 & 0xFFFFu) | (((uint)(vv0 >> 32) & 0xFFFFu) << 16);
                w.y = ((uint)vv1 & 0xFFFFu) | (((uint)(vv1 >> 32) & 0xFFFFu) << 16);
                *(uint2*)(hb + b * 528 + c0 * 4) = w;
            }
            __syncthreads();  // the ONLY barrier per step (Hs dbuf covers the rest)
            // h-part MFMAs: frag = Hs[t&1][row=l16][units s*32+quad*8 ..+8], both tiles.
#pragma unroll
            for (int s = 0; s < 8; ++s) {
                bf16x8 bh = *(const bf16x8*)(hb + l16 * 528 + s * 64 + quad * 16);
                A0 = __builtin_amdgcn_mfma_f32_16x16x32_bf16(af0[2 + s], bh, A0, 0, 0, 0);
                A1 = __builtin_amdgcn_mfma_f32_16x16x32_bf16(af1[2 + s], bh, A1, 0, 0, 0);
            }
        }
        // Epilogue: lane owns (u0,bb) and (u1,bb).
        float hv0, hv1;
        {
            float gi = A0[0] + bi0, gf = A0[1] + bf0, gg = A0[2] + bg0, go = A0[3] + bo0;
            float ii = sigmoidf_(gi), ff = sigmoidf_(gf), g2 = tanhf_(gg), oo = sigmoidf_(go);
            cs0 = ff * cs0 + ii * g2;
            hv0 = oo * tanhf_(cs0);
        }
        {
            float gi = A1[0] + bi1, gf = A1[1] + bf1, gg = A1[2] + bg1, go = A1[3] + bo1;
            float ii = sigmoidf_(gi), ff = sigmoidf_(gf), g2 = tanhf_(gg), oo = sigmoidf_(go);
            cs1 = ff * cs1 + ii * g2;
            hv1 = oo * tanhf_(cs1);
        }
        if (t == TC_ - 1) {
            hfin[u0 * 64 + bb] = hv0;
            hfin[u1 * 64 + bb] = hv1;
        } else {
            // Publish: pack unit pairs via shfl (quad gets quad+1's value, same l16);
            // ATOMIC stores (R6/R8-proven visibility path).
            ushort h0 = f2bf(hv0), h1 = f2bf(hv1);
            uint pr0 = ((uint)h0 & 0xFFFFu) | ((uint)__shfl((int)h0, (lane + 16) & 63) << 16);
            uint pr1 = ((uint)h1 & 0xFFFFu) | ((uint)__shfl((int)h1, (lane + 16) & 63) << 16);
            if ((quad & 1) == 0) {
                uint tg2 = ((uint)t) << 16;
                u64 w0 = (u64)((pr0 & 0xFFFFu) | tg2) | ((u64)((pr0 >> 16) | tg2) << 32);
                u64 w1 = (u64)((pr1 & 0xFFFFu) | tg2) | ((u64)((pr1 >> 16) | tg2) << 32);
                u64* dst = hbuf + ((size_t)(t & 1) << 13) + p * 2048 + l16 * 128;
                __hip_atomic_store(dst + pc, w0, __ATOMIC_RELAXED, __HIP_MEMORY_SCOPE_AGENT);
                __hip_atomic_store(dst + pc + 2, w1, __ATOMIC_RELAXED, __HIP_MEMORY_SCOPE_AGENT);
            }
        }
        // Prefetch next xt (fire after publish; lands during next poll).
        int tn = (t + 1 < TC_) ? t + 1 : t;
        const ushort* xpn = li + ((size_t)tn * 64 + bb) * 72 + quad * 8;
        x0 = *(const bf16x8*)xpn;
        x1 = *(const bf16x8*)(xpn + 32);
    }
}

// ---- Kernel 5: out[b][o] = h_final[:,b] . lin_w[o,:] + lin_b[o] ----
__global__ __launch_bounds__(64) void k_fin(const float* __restrict__ hfin, const float* __restrict__ lw,
                                            const float* __restrict__ lb, float* __restrict__ out) {
    int o = blockIdx.x, b = threadIdx.x;
    float acc = lb[o];
    const float* wp = lw + o * 256;
#pragma unroll 4
    for (int u2 = 0; u2 < 256; ++u2) acc += hfin[u2 * 64 + b] * wp[u2];
    out[b * 10 + o] = acc;
}

extern "C" void kernel_launch(void* const* d_in, const int* in_sizes, int n_in,
                              void* d_out, int out_size, void* d_ws, size_t ws_size,
                              hipStream_t stream) {
    const float* in  = (const float*)d_in[0];
    // d_in[1] ("r") unused
    const float* cw  = (const float*)d_in[2];
    const float* cb  = (const float*)d_in[3];
    const float* wih = (const float*)d_in[4];
    const float* whh = (const float*)d_in[5];
    const float* bih = (const float*)d_in[6];
    const float* bhh = (const float*)d_in[7];
    const float* lw  = (const float*)d_in[8];
    const float* lb  = (const float*)d_in[9];
    float* out = (float*)d_out;

    char* ws = (char*)d_ws;
    float*  sq   = (float*)(ws + 0);          // 32768 B
    u64*    hbuf = (u64*)(ws + 32768);        // 131072 B: 2 parity x (4 pods x 2048 cells) x 8B
    float*  bias = (float*)(ws + 163840);     // 4096 B
    float*  hfin = (float*)(ws + 167936);     // 65536 B  [u][b] fp32
    ushort* wbf  = (ushort*)(ws + 233472);    // 655360 B [g2][16][320] bf16
    ushort* li   = (ushort*)(ws + 888832);    // 9418752 B [tc][b][72] bf16

    hipMemsetAsync(sq, 0, 32768, stream);
    hipMemsetAsync(hbuf, 0xFF, 131072, stream);  // tag fields -> 0xFFFF, never a valid step

    k_sqsum<<<1024, 128, 0, stream>>>(in, sq);
    k_prep<<<1280, 256, 0, stream>>>(wih, whh, bih, bhh, wbf, bias);
    k_conv<<<2048, 256, 0, stream>>>(in, cw, cb, sq, li);
    // 16 blocks x 1024 thr: pod p = blockIdx%8 (XCD under round-robin dispatch),
    // role q = blockIdx/8. Pods 0-3 get 2 same-XCD blocks each; p>=4 exit at once.
    k_scan<<<16, 1024, 0, stream>>>(li, wbf, bias, hbuf, hfin);
    k_fin<<<10, 64, 0, stream>>>(hfin, lw, lb, out);
}

// Round 15
// 2682.470 us; speedup vs baseline: 2.9243x; 2.7244x over previous
//
#include <hip/hip_runtime.h>
#include <stdint.h>

#define B_ 64
#define T_ 2048
#define F_ 128
#define H_ 256
#define TC_ 1022

typedef __bf16 bf16x8 __attribute__((ext_vector_type(8)));
typedef float f32x4 __attribute__((ext_vector_type(4)));
typedef uint u32x4 __attribute__((ext_vector_type(4)));
typedef unsigned long long u64;

__device__ __forceinline__ ushort f2bf(float f) {
    uint32_t u = __builtin_bit_cast(uint32_t, f);
    u += 0x7FFFu + ((u >> 16) & 1u);
    return (ushort)(u >> 16);
}
__device__ __forceinline__ float sigmoidf_(float x) {
    return __builtin_amdgcn_rcpf(1.f + __expf(-x));
}
__device__ __forceinline__ float tanhf_(float x) {
    x = fminf(15.f, fmaxf(-15.f, x));
    float e = __expf(2.f * x);
    return 1.f - 2.f * __builtin_amdgcn_rcpf(e + 1.f);
}

// ---- Kernel 1: sum of squares over T for F.normalize(dim=1) ----
__global__ __launch_bounds__(128) void k_sqsum(const float* __restrict__ in,
                                               float* __restrict__ sq) {
    int b = blockIdx.x >> 4, tq = blockIdx.x & 15, f = threadIdx.x;
    const float* p = in + ((size_t)b * T_ + (size_t)tq * 128) * F_ + f;
    float acc = 0.f;
#pragma unroll 8
    for (int t = 0; t < 128; ++t) { float v = p[(size_t)t * F_]; acc += v * v; }
    atomicAdd(&sq[b * F_ + f], acc);
}

// ---- Kernel 2: weight repack to bf16 block-row order; bias combine ----
// wbf[g2][m][k]: g2 = unit>>2 (0..63), m = uu*4+gate, k: [0,64)=w_ih, [64,320)=w_hh
__global__ __launch_bounds__(256) void k_prep(const float* __restrict__ wih, const float* __restrict__ whh,
                                              const float* __restrict__ bih, const float* __restrict__ bhh,
                                              ushort* __restrict__ wbf, float* __restrict__ bias) {
    int e = blockIdx.x * 256 + threadIdx.x;
    if (e < 64 * 16 * 320) {
        int g = e / 5120, m = (e / 320) & 15, k = e % 320;
        int j = (m & 3) * 256 + g * 4 + (m >> 2);  // gate*256 + unit
        float v = (k < 64) ? wih[j * 64 + k] : whh[j * 256 + (k - 64)];
        wbf[e] = f2bf(v);
    }
    if (e < 1024) bias[e] = bih[e] + bhh[e];
}

// ---- Kernel 3: fused normalize + conv1d(K=5,S=2) + bias + relu -> li bf16 [tc][b][72pad] ----
__global__ __launch_bounds__(256) void k_conv(const float* __restrict__ in, const float* __restrict__ cw,
                                              const float* __restrict__ cb, const float* __restrict__ sq,
                                              ushort* __restrict__ li) {
    __shared__ float rn[128];
    __shared__ __align__(16) float xs[67 * 129];
    __shared__ __align__(16) float wl[80 * 68];
    int b = blockIdx.x >> 5, tile = blockIdx.x & 31;
    int tc0 = tile * 32;
    int tid = threadIdx.x;
    if (tid < 128) { float ss = sq[b * 128 + tid]; rn[tid] = 1.f / fmaxf(sqrtf(ss), 1e-12f); }
    __syncthreads();
    const float* ip = in + ((size_t)b * T_ + (size_t)(2 * tc0)) * F_;
    for (int i = tid; i < 67 * 128; i += 256) {
        int r = i >> 7, f = i & 127;
        int t = 2 * tc0 + r;
        xs[r * 129 + f] = (t < T_) ? ip[(size_t)r * F_ + f] * rn[f] : 0.f;
    }
    int cg = tid & 15, tcg = tid >> 4;
    float a00 = 0, a01 = 0, a10 = 0, a11 = 0, a20 = 0, a21 = 0, a30 = 0, a31 = 0;
    for (int fc = 0; fc < 8; ++fc) {
        __syncthreads();
        for (int i = tid; i < 64 * 80; i += 256) {
            int c = i / 80, j = i - c * 80;
            wl[j * 68 + c] = cw[c * 640 + fc * 80 + j];
        }
        __syncthreads();
#pragma unroll
        for (int fi = 0; fi < 16; ++fi) {
#pragma unroll
            for (int k = 0; k < 5; ++k) {
                const float4 w4 = *(const float4*)&wl[(fi * 5 + k) * 68 + cg * 4];
                float x0 = xs[(4 * tcg + k) * 129 + fc * 16 + fi];
                float x1 = xs[(4 * tcg + 2 + k) * 129 + fc * 16 + fi];
                a00 += w4.x * x0; a01 += w4.x * x1;
                a10 += w4.y * x0; a11 += w4.y * x1;
                a20 += w4.z * x0; a21 += w4.z * x1;
                a30 += w4.w * x0; a31 += w4.w * x1;
            }
        }
    }
    float bc0 = cb[cg * 4 + 0], bc1 = cb[cg * 4 + 1], bc2 = cb[cg * 4 + 2], bc3 = cb[cg * 4 + 3];
#pragma unroll
    for (int tt = 0; tt < 2; ++tt) {
        int tc = tc0 + tcg * 2 + tt;
        if (tc < TC_) {
            float v0 = fmaxf((tt ? a01 : a00) + bc0, 0.f);
            float v1 = fmaxf((tt ? a11 : a10) + bc1, 0.f);
            float v2 = fmaxf((tt ? a21 : a20) + bc2, 0.f);
            float v3 = fmaxf((tt ? a31 : a30) + bc3, 0.f);
            uint2 pk;
            pk.x = (uint32_t)f2bf(v0) | ((uint32_t)f2bf(v1) << 16);
            pk.y = (uint32_t)f2bf(v2) | ((uint32_t)f2bf(v3) << 16);
            *reinterpret_cast<uint2*>(&li[((size_t)tc * 64 + b) * 72 + cg * 4]) = pk;
        }
    }
}

// ---- Kernel 4: pod-structured LSTM scan — ATOMIC publish + PLAIN-sc0 poll, XCD-local.
// FINAL (R8-proven, best-measured 2411us total). Session ledger: 11 exchange
// protocol/placement variants (tagged/L2, tagged/MALL-bypass, flag/MALL, plain/plain,
// atomic/plain x cross/same-XCD placements) all land at ~5.2-6.4k cy/step; single-CU
// no-exchange designs are closed by storage arithmetic (512KB bf16 weights cannot be
// CU-resident: 256-VGPR/wave arch cap + 160KB LDS; streaming the residual is
// BW-floored above this kernel); pod-width tests (dual-group R1/R10, 2-block R14)
// null or confounded-worse. Conclusion: per-step cost ~= 2 serial MALL-visibility
// legs (~2.5k cy each) + ~1k cy compute — a latency-structural floor of the gfx950
// cross-CU coherence model, not a pipe roofline (all pipes <1% busy).
// Placement: p=blockIdx%8 -> pod's 4 blocks share one XCD (FETCH 154->40MB, R6-proven).
// Protocol: tagged cells (tag in each 32b half -> torn reads self-detect), parity
// double-buffer, atomic publish (R6-proven visibility) + plain-sc0 fast poll with
// sticky atomic fallback, Hs double-buffer -> single barrier/step. Chain argument
// bounds intra-pod skew <= 1.
__global__ __launch_bounds__(512) void k_scan(const ushort* __restrict__ li,
                                              const ushort* __restrict__ wbf,
                                              const float* __restrict__ bias,
                                              u64* __restrict__ hbuf,
                                              float* __restrict__ hfin) {
    __shared__ __align__(16) ushort Hs[2][16 * 264];  // dbuf: h [b:16][256+8 pad], rows 528B
    int p = blockIdx.x & 7, q = blockIdx.x >> 3;
    if (p >= 4) return;                       // only XCDs 0-3 host pods; others exit
    int tid = threadIdx.x;
    int lane = tid & 63, wave = tid >> 6, l16 = lane & 15, quad = lane >> 4;
    int bb = p * 16 + l16;                    // global batch
    int g2a = q * 16 + 2 * wave, g2b = g2a + 1;
    int u0 = g2a * 4 + quad, u1 = g2b * 4 + quad;
    int pc = 32 * q + 4 * wave + (quad >> 1); // publish pair-cell (tile0; tile1 = +2)
    // Stationary A-fragments: two 16-row tiles (rows = l16 within each tile).
    bf16x8 af0[10], af1[10];
    const ushort* wp0 = wbf + ((size_t)(g2a * 16 + l16)) * 320 + quad * 8;
    const ushort* wp1 = wbf + ((size_t)(g2b * 16 + l16)) * 320 + quad * 8;
#pragma unroll
    for (int s = 0; s < 10; ++s) { af0[s] = *(const bf16x8*)(wp0 + s * 32);
                                   af1[s] = *(const bf16x8*)(wp1 + s * 32); }
    float bi0 = bias[u0], bf0 = bias[256 + u0], bg0 = bias[512 + u0], bo0 = bias[768 + u0];
    float bi1 = bias[u1], bf1 = bias[256 + u1], bg1 = bias[512 + u1], bo1 = bias[768 + u1];
    float cs0 = 0.f, cs1 = 0.f;
    bool broken = false;
    // xt preload for t=0 (B-frags shared by both M-tiles)
    const ushort* xpp = li + ((size_t)0 * 64 + bb) * 72 + quad * 8;
    bf16x8 x0 = *(const bf16x8*)xpp;
    bf16x8 x1 = *(const bf16x8*)(xpp + 32);
#pragma unroll 1
    for (int t = 0; t < TC_; ++t) {
        f32x4 A0 = {0.f, 0.f, 0.f, 0.f}, A1 = {0.f, 0.f, 0.f, 0.f};
        // x-part MFMAs first (xt already in regs from prefetch).
        A0 = __builtin_amdgcn_mfma_f32_16x16x32_bf16(af0[0], x0, A0, 0, 0, 0);
        A1 = __builtin_amdgcn_mfma_f32_16x16x32_bf16(af1[0], x0, A1, 0, 0, 0);
        A0 = __builtin_amdgcn_mfma_f32_16x16x32_bf16(af0[1], x1, A0, 0, 0, 0);
        A1 = __builtin_amdgcn_mfma_f32_16x16x32_bf16(af1[1], x1, A1, 0, 0, 0);
        char* hb = (char*)Hs + (size_t)(t & 1) * (16 * 264 * 2);  // this step's h buffer
        if (t > 0) {
            uint tg = (uint)(t - 1);
            const u64* src = hbuf + ((size_t)((t - 1) & 1) << 13) + p * 2048 + tid * 4;
            u64 vv0, vv1, vv2, vv3;
            bool got = false;
            if (!broken) {
                // FAST poll: plain sc0 dwordx4 loads (L1-bypass, L2-served).
                u32x4 pa, pb;
                bool ok;
                int guard = 0;
                do {
                    asm volatile(
                        "global_load_dwordx4 %0, %2, off sc0\n\t"
                        "global_load_dwordx4 %1, %2, off offset:16 sc0\n\t"
                        "s_waitcnt vmcnt(0)"
                        : "=&v"(pa), "=&v"(pb)
                        : "v"(src)
                        : "memory");
                    uint m = ((pa.x >> 16) ^ tg) | ((pa.y >> 16) ^ tg)
                           | ((pa.z >> 16) ^ tg) | ((pa.w >> 16) ^ tg)
                           | ((pb.x >> 16) ^ tg) | ((pb.y >> 16) ^ tg)
                           | ((pb.z >> 16) ^ tg) | ((pb.w >> 16) ^ tg);
                    ok = (m == 0);
                } while (!__all(ok) && ++guard < 1024);
                got = __all(ok);
                if (got) {
                    vv0 = ((u64)pa.y << 32) | pa.x;
                    vv1 = ((u64)pa.w << 32) | pa.z;
                    vv2 = ((u64)pb.y << 32) | pb.x;
                    vv3 = ((u64)pb.w << 32) | pb.z;
                } else {
                    broken = true;  // sticky: this wave polls atomically from now on
                }
            }
            if (!got) {
                // Fallback: R6-proven atomic-load poll on the SAME cells.
                u64 w0, w1, w2, w3;
                bool ok;
                int guard = 0;
                do {
                    w0 = __hip_atomic_load(src + 0, __ATOMIC_RELAXED, __HIP_MEMORY_SCOPE_AGENT);
                    w1 = __hip_atomic_load(src + 1, __ATOMIC_RELAXED, __HIP_MEMORY_SCOPE_AGENT);
                    w2 = __hip_atomic_load(src + 2, __ATOMIC_RELAXED, __HIP_MEMORY_SCOPE_AGENT);
                    w3 = __hip_atomic_load(src + 3, __ATOMIC_RELAXED, __HIP_MEMORY_SCOPE_AGENT);
                    uint m = (((uint)(w0 >> 16) & 0xFFFFu) ^ tg) | (((uint)(w0 >> 48)) ^ tg);
                    m |= (((uint)(w1 >> 16) & 0xFFFFu) ^ tg) | (((uint)(w1 >> 48)) ^ tg);
                    m |= (((uint)(w2 >> 16) & 0xFFFFu) ^ tg) | (((uint)(w2 >> 48)) ^ tg);
                    m |= (((uint)(w3 >> 16) & 0xFFFFu) ^ tg) | (((uint)(w3 >> 48)) ^ tg);
                    ok = (m == 0);
                } while (!__all(ok) && ++guard < (1 << 14));
                vv0 = w0; vv1 = w1; vv2 = w2; vv3 = w3;
            }
            // Stage to LDS dbuf: idx=4*tid -> b=idx>>7, c=idx&127; cell c = units {2c,2c+1}.
            {
                int b = tid >> 5, c0 = (tid * 4) & 127;
                uint4 w;
                w.x = ((uint)vv0 & 0xFFFFu) | (((uint)(vv0 >> 32) & 0xFFFFu) << 16);
                w.y = ((uint)vv1 & 0xFFFFu) | (((uint)(vv1 >> 32) & 0xFFFFu) << 16);
                w.z = ((uint)vv2 & 0xFFFFu) | (((uint)(vv2 >> 32) & 0xFFFFu) << 16);
                w.w = ((uint)vv3 & 0xFFFFu) | (((uint)(vv3 >> 32) & 0xFFFFu) << 16);
                *(uint4*)(hb + b * 528 + c0 * 4) = w;
            }
            __syncthreads();  // the ONLY barrier per step (Hs dbuf makes the 2nd redundant)
            // h-part MFMAs: frag = Hs[t&1][row=l16][units s*32+quad*8 ..+8], both tiles.
#pragma unroll
            for (int s = 0; s < 8; ++s) {
                bf16x8 bh = *(const bf16x8*)(hb + l16 * 528 + s * 64 + quad * 16);
                A0 = __builtin_amdgcn_mfma_f32_16x16x32_bf16(af0[2 + s], bh, A0, 0, 0, 0);
                A1 = __builtin_amdgcn_mfma_f32_16x16x32_bf16(af1[2 + s], bh, A1, 0, 0, 0);
            }
        }
        // Epilogue: lane owns (u0,bb) and (u1,bb).
        float hv0, hv1;
        {
            float gi = A0[0] + bi0, gf = A0[1] + bf0, gg = A0[2] + bg0, go = A0[3] + bo0;
            float ii = sigmoidf_(gi), ff = sigmoidf_(gf), g2 = tanhf_(gg), oo = sigmoidf_(go);
            cs0 = ff * cs0 + ii * g2;
            hv0 = oo * tanhf_(cs0);
        }
        {
            float gi = A1[0] + bi1, gf = A1[1] + bf1, gg = A1[2] + bg1, go = A1[3] + bo1;
            float ii = sigmoidf_(gi), ff = sigmoidf_(gf), g2 = tanhf_(gg), oo = sigmoidf_(go);
            cs1 = ff * cs1 + ii * g2;
            hv1 = oo * tanhf_(cs1);
        }
        if (t == TC_ - 1) {
            hfin[u0 * 64 + bb] = hv0;
            hfin[u1 * 64 + bb] = hv1;
        } else {
            // Publish: pack unit pairs via shfl (quad gets quad+1's value, same l16);
            // ATOMIC stores (R6-proven visible to same-XCD consumers).
            ushort h0 = f2bf(hv0), h1 = f2bf(hv1);
            uint pr0 = ((uint)h0 & 0xFFFFu) | ((uint)__shfl((int)h0, (lane + 16) & 63) << 16);
            uint pr1 = ((uint)h1 & 0xFFFFu) | ((uint)__shfl((int)h1, (lane + 16) & 63) << 16);
            if ((quad & 1) == 0) {
                uint tg2 = ((uint)t) << 16;
                u64 w0 = (u64)((pr0 & 0xFFFFu) | tg2) | ((u64)((pr0 >> 16) | tg2) << 32);
                u64 w1 = (u64)((pr1 & 0xFFFFu) | tg2) | ((u64)((pr1 >> 16) | tg2) << 32);
                u64* dst = hbuf + ((size_t)(t & 1) << 13) + p * 2048 + l16 * 128;
                __hip_atomic_store(dst + pc, w0, __ATOMIC_RELAXED, __HIP_MEMORY_SCOPE_AGENT);
                __hip_atomic_store(dst + pc + 2, w1, __ATOMIC_RELAXED, __HIP_MEMORY_SCOPE_AGENT);
            }
        }
        // Prefetch next xt (fire after publish; lands during next poll).
        int tn = (t + 1 < TC_) ? t + 1 : t;
        const ushort* xpn = li + ((size_t)tn * 64 + bb) * 72 + quad * 8;
        x0 = *(const bf16x8*)xpn;
        x1 = *(const bf16x8*)(xpn + 32);
    }
}

// ---- Kernel 5: out[b][o] = h_final[:,b] . lin_w[o,:] + lin_b[o] ----
__global__ __launch_bounds__(64) void k_fin(const float* __restrict__ hfin, const float* __restrict__ lw,
                                            const float* __restrict__ lb, float* __restrict__ out) {
    int o = blockIdx.x, b = threadIdx.x;
    float acc = lb[o];
    const float* wp = lw + o * 256;
#pragma unroll 4
    for (int u2 = 0; u2 < 256; ++u2) acc += hfin[u2 * 64 + b] * wp[u2];
    out[b * 10 + o] = acc;
}

extern "C" void kernel_launch(void* const* d_in, const int* in_sizes, int n_in,
                              void* d_out, int out_size, void* d_ws, size_t ws_size,
                              hipStream_t stream) {
    const float* in  = (const float*)d_in[0];
    // d_in[1] ("r") unused
    const float* cw  = (const float*)d_in[2];
    const float* cb  = (const float*)d_in[3];
    const float* wih = (const float*)d_in[4];
    const float* whh = (const float*)d_in[5];
    const float* bih = (const float*)d_in[6];
    const float* bhh = (const float*)d_in[7];
    const float* lw  = (const float*)d_in[8];
    const float* lb  = (const float*)d_in[9];
    float* out = (float*)d_out;

    char* ws = (char*)d_ws;
    float*  sq   = (float*)(ws + 0);          // 32768 B
    u64*    hbuf = (u64*)(ws + 32768);        // 131072 B: 2 parity x (4 pods x 2048 cells) x 8B
    float*  bias = (float*)(ws + 163840);     // 4096 B
    float*  hfin = (float*)(ws + 167936);     // 65536 B  [u][b] fp32
    ushort* wbf  = (ushort*)(ws + 233472);    // 655360 B [g2][16][320] bf16
    ushort* li   = (ushort*)(ws + 888832);    // 9418752 B [tc][b][72] bf16

    hipMemsetAsync(sq, 0, 32768, stream);
    hipMemsetAsync(hbuf, 0xFF, 131072, stream);  // tag fields -> 0xFFFF, never a valid step

    k_sqsum<<<1024, 128, 0, stream>>>(in, sq);
    k_prep<<<1280, 256, 0, stream>>>(wih, whh, bih, bhh, wbf, bias);
    k_conv<<<2048, 256, 0, stream>>>(in, cw, cb, sq, li);
    // 32 blocks: pod p = blockIdx%8 (XCD under round-robin dispatch), q = blockIdx/8.
    // Pods live on XCDs 0-3 (4 same-XCD blocks each); blocks with p>=4 exit at once.
    k_scan<<<32, 512, 0, stream>>>(li, wbf, bias, hbuf, hfin);
    k_fin<<<10, 64, 0, stream>>>(hfin, lw, lb, out);
}